// Round 13
// baseline (1800.908 us; speedup 1.0000x reference)
//
#include <hip/hip_runtime.h>
#include <hip/hip_bf16.h>
#include <cstdint>
#include <cstdio>

using bf16 = __hip_bfloat16;
typedef __attribute__((ext_vector_type(8))) short bf16x8;
typedef __attribute__((ext_vector_type(4))) float f32x4;
typedef __attribute__((ext_vector_type(16))) float f32x16;

__device__ __forceinline__ void gload_lds16(const void* g, void* l) {
  __builtin_amdgcn_global_load_lds((__attribute__((address_space(1))) void*)g,
                                   (__attribute__((address_space(3))) void*)l,
                                   16, 0, 0);
}

__device__ __forceinline__ float bfu2f(unsigned short u) {
  return __uint_as_float((unsigned int)u << 16);
}
__device__ __forceinline__ unsigned short f2bfu(float f) {
  bf16 b = __float2bfloat16(f);
  return *(unsigned short*)&b;
}

enum { EP_NONE = 0, EP_SILU = 1, EP_MISH = 2, EP_RES = 3, EP_RESB = 4 };

// ---------------------------------------------------------------------------
// 256x256-tile quad-phase bf16 MFMA GEMM, 32x32x16 shape (r13).
// r12 skeleton (quad phases, vmcnt(6) once/K-tile, 1 barrier/phase, stage
// schedule verified) with v_mfma_f32_32x32x16_bf16: half the MFMA instr
// count per phase (8 vs 16), +15% ceiling, same ds_read count, same acc VGPR.
// Wave slice per quad = 64x32 -> 2i x 1j frags of 32x32, 4 k-slices (BK=64).
// A/B operand: lane holds row/col = lane&31, k-octet = lane>>5.
// C/D: col = lane&31, row = (reg&3) + 8*(reg>>2) + 4*(lane>>5)  [m74/m101].
// Requires: M%256==0, N%256==0 (stride), K%64==0, K/64>=3.
// ---------------------------------------------------------------------------
template<int EPI>
__global__ __launch_bounds__(512, 1)
void gemm256(const bf16* __restrict__ A, const bf16* __restrict__ Bt,
             int N, int Nb, int K, int gy,
             const float* __restrict__ bias,
             const float* __restrict__ residf,
             const bf16* __restrict__ residb,
             bf16* __restrict__ outb)
{
  __shared__ char lds[131072];
  const int tid  = threadIdx.x;
  const int lane = tid & 63;
  const int wid  = tid >> 6;
  const int wm = wid >> 2, wn = wid & 3;     // 2 x 4 waves per quadrant
  const int l31 = lane & 31, l5 = lane >> 5;

  // bijective XCD-chunked remap; bx-major (r10: lowest HBM traffic)
  const int nwg = gridDim.x;
  const int q8 = nwg >> 3, r8 = nwg & 7;
  const int xcd = blockIdx.x & 7, idx = blockIdx.x >> 3;
  const int wg2 = (xcd < r8 ? xcd * (q8 + 1) : r8 * (q8 + 1) + (xcd - r8) * q8) + idx;
  const int bx = wg2 / gy, by = wg2 % gy;
  const long brow = (long)bx * 256, bcol = (long)by * 256;

  const size_t rb = (size_t)K * 2;                   // bytes per row
  const int srow8 = wid * 8 + (lane >> 3);           // staging row in 64-block
  const int coff  = ((lane & 7) ^ (lane >> 3)) << 4; // pre-swizzled chunk
  const char* aS = (const char*)A  + (size_t)(brow + srow8) * rb + coff;
  const char* bS = (const char*)Bt + (size_t)(bcol + srow8) * rb + coff;
  char* ldsA = lds;
  char* ldsB = lds + 65536;
  const int luni = wid * 1024;

  const int kt = K >> 6;

  // stage half h (128 rows) of operand tile t: 2 block-wide gloads (16 KB)
  auto stA = [&](int t, int h) {
    const char* s = aS + (size_t)(h * 128) * rb + (size_t)t * 128;
    char* d = ldsA + (t & 1) * 32768 + h * 16384 + luni;
    gload_lds16(s, d);
    gload_lds16(s + (size_t)64 * rb, d + 8192);
  };
  auto stB = [&](int t, int h) {
    const char* s = bS + (size_t)(h * 128) * rb + (size_t)t * 128;
    char* d = ldsB + (t & 1) * 32768 + h * 16384 + luni;
    gload_lds16(s, d);
    gload_lds16(s + (size_t)64 * rb, d + 8192);
  };

  f32x16 acc[4][2] = {};       // [quad][i]
  bf16x8 afr[2][4], bfr[4];    // [i][ks], [ks]

  // prologue: 7 half-tiles in steady-state-compatible issue order (r12 ledger)
  stA(0, 0); stB(0, 0); stB(0, 1); stA(0, 1);
  stA(1, 0); stB(1, 1); stA(1, 1);

  // LDS addressing: row-major 128B rows, chunk c (16B) swizzled c ^= row&7.
  // A-frag (i,ks): row = wm*64 + i*32 + l31, chunk = ks*2 + l5.
  const int arow0 = wm * 64 + l31;   // + i*32
  const int brw0  = wn * 32 + l31;

#define KCH(base_row, ks) ((((ks) * 2 + l5) ^ ((base_row) & 7)) << 4)
#define RD_A(rh) \
  _Pragma("unroll") for (int i = 0; i < 2; i++) \
  _Pragma("unroll") for (int ks = 0; ks < 4; ks++) \
    afr[i][ks] = *(const bf16x8*)(pA + (rh) * 16384 + (arow0 + i * 32) * 128 + KCH(arow0 + i * 32, ks));
#define RD_B(ch) \
  _Pragma("unroll") for (int ks = 0; ks < 4; ks++) \
    bfr[ks] = *(const bf16x8*)(pB + (ch) * 16384 + brw0 * 128 + KCH(brw0, ks));
#define MFMA_Q(q) \
  asm volatile("s_waitcnt lgkmcnt(0)" ::: "memory"); \
  __builtin_amdgcn_sched_barrier(0); \
  __builtin_amdgcn_s_setprio(1); \
  _Pragma("unroll") for (int i = 0; i < 2; i++) \
  _Pragma("unroll") for (int ks = 0; ks < 4; ks++) \
    acc[q][i] = __builtin_amdgcn_mfma_f32_32x32x16_bf16(afr[i][ks], bfr[ks], acc[q][i], 0, 0, 0); \
  __builtin_amdgcn_s_setprio(0);

  for (int t = 0; t < kt; ++t) {
    const char* pA = ldsA + (t & 1) * 32768;
    const char* pB = ldsB + (t & 1) * 32768;

    // ---- ph0: quad (A0,B0) ----
    if (t + 1 < kt) asm volatile("s_waitcnt vmcnt(6)" ::: "memory");
    else            asm volatile("s_waitcnt vmcnt(0)" ::: "memory");
    __builtin_amdgcn_s_barrier();
    RD_A(0) RD_B(0)
    if (t + 1 < kt) stB(t + 1, 0);
    MFMA_Q(0)

    // ---- ph1: quad (A0,B1) — reuse afr ----
    __builtin_amdgcn_s_barrier();
    RD_B(1)
    if (t + 2 < kt) stA(t + 2, 0);
    MFMA_Q(1)

    // ---- ph2: quad (A1,B1) — reuse bfr ----
    __builtin_amdgcn_s_barrier();
    RD_A(1)
    if (t + 2 < kt) stB(t + 2, 1);
    MFMA_Q(2)

    // ---- ph3: quad (A1,B0) — reuse afr, re-read B0 ----
    __builtin_amdgcn_s_barrier();
    RD_B(0)
    if (t + 2 < kt) stA(t + 2, 1);
    MFMA_Q(3)
  }
#undef KCH
#undef RD_A
#undef RD_B
#undef MFMA_Q

  __syncthreads();

  // ---- epilogue: bias(+act) -> LDS (swizzled) -> coalesced bf16x8 stores ----
  char* lC = lds;
#pragma unroll
  for (int q = 0; q < 4; q++) {
    const int rh = (q >= 2), ch = (q == 1 || q == 2);
    const int tcol = ch * 128 + wn * 32 + l31;
    const long gcol = bcol + tcol;
    const float bv = (gcol < Nb) ? bias[gcol] : 0.f;
#pragma unroll
    for (int i = 0; i < 2; i++) {
#pragma unroll
      for (int r = 0; r < 16; r++) {
        const int row = rh * 128 + wm * 64 + i * 32 + (r & 3) + 8 * (r >> 2) + 4 * l5;
        float v = acc[q][i][r] + bv;
        if constexpr (EPI == EP_MISH) {
          float e = __expf(fminf(v, 20.f));
          float u = (1.f + e); u *= u;
          v = v * (u - 1.f) / (u + 1.f);
        }
        *(unsigned short*)(lC + row * 512 + ((tcol * 2) ^ ((row & 12) << 3))) = f2bfu(v);
      }
    }
  }
  __syncthreads();
  const int trow = tid >> 5;
  const int tcb  = (tid & 31) * 16;
#pragma unroll
  for (int it = 0; it < 16; ++it) {
    const int row = it * 16 + trow;
    bf16x8 vv = *(const bf16x8*)(lC + row * 512 + (tcb ^ ((row & 12) << 3)));
    const long grow = brow + row;
    bf16* dst = outb + grow * (long)N + bcol + (tcb >> 1);
    if constexpr (EPI == EP_RES) {
      const float* rs = residf + grow * (long)N + bcol + (tcb >> 1);
      float4 ra = *(const float4*)rs, rb2 = *(const float4*)(rs + 4);
      float rv[8] = {ra.x, ra.y, ra.z, ra.w, rb2.x, rb2.y, rb2.z, rb2.w};
      bf16x8 ov;
#pragma unroll
      for (int e = 0; e < 8; e++)
        ov[e] = (short)f2bfu(bfu2f((unsigned short)vv[e]) + rv[e]);
      *(bf16x8*)dst = ov;
    } else if constexpr (EPI == EP_RESB) {
      bf16x8 rb3 = *(const bf16x8*)(residb + grow * (long)N + bcol + (tcb >> 1));
      bf16x8 ov;
#pragma unroll
      for (int e = 0; e < 8; e++)
        ov[e] = (short)f2bfu(bfu2f((unsigned short)vv[e]) + bfu2f((unsigned short)rb3[e]));
      *(bf16x8*)dst = ov;
    } else {
      *(bf16x8*)dst = vv;
    }
  }
}

// ---------------------------------------------------------------------------
// 128x128-tile bf16 MFMA GEMM (m97 structure) — small smolgen GEMMs.
// ---------------------------------------------------------------------------
template<int EPI, bool OUTF>
__global__ __launch_bounds__(256)
void gemm_kernel(const bf16* __restrict__ A, const bf16* __restrict__ Bt,
                 int M, int N, int K,
                 const float* __restrict__ bias,
                 const float* __restrict__ residf,
                 const bf16* __restrict__ residb,
                 float* __restrict__ outf, bf16* __restrict__ outb)
{
  __shared__ bf16 lA[128 * 32];
  __shared__ bf16 lB[128 * 32];
  const int tid  = threadIdx.x;
  const int lane = tid & 63;
  const int wvid = tid >> 6;
  const int wr = (wvid >> 1) * 64;
  const int wc = (wvid & 1) * 64;
  const long brow = (long)blockIdx.x * 128;
  const long bcol = (long)blockIdx.y * 128;
  const int lr = lane & 15;
  const int k8 = (lane >> 4) * 8;

  const int lofs0 = wvid * 1024;
  const int lofs1 = lofs0 + 4096;
  const int o0 = lofs0 + lane * 16;
  const int o1 = o0 + 4096;
  const int r0 = o0 >> 6, c0 = o0 & 63;
  const int r1 = o1 >> 6, c1 = o1 & 63;

  f32x4 acc[4][4] = {};

  for (int k0 = 0; k0 < K; k0 += 32) {
    const long kb = (long)k0 * 2;
    gload_lds16((const char*)A  + ((brow + r0) * (long)K) * 2 + kb + c0, (char*)lA + lofs0);
    gload_lds16((const char*)A  + ((brow + r1) * (long)K) * 2 + kb + c1, (char*)lA + lofs1);
    gload_lds16((const char*)Bt + ((bcol + r0) * (long)K) * 2 + kb + c0, (char*)lB + lofs0);
    gload_lds16((const char*)Bt + ((bcol + r1) * (long)K) * 2 + kb + c1, (char*)lB + lofs1);
    __syncthreads();
    bf16x8 af[4], bf_[4];
#pragma unroll
    for (int i = 0; i < 4; i++)
      af[i] = *(const bf16x8*)&lA[(wr + i * 16 + lr) * 32 + k8];
#pragma unroll
    for (int j = 0; j < 4; j++)
      bf_[j] = *(const bf16x8*)&lB[(wc + j * 16 + lr) * 32 + k8];
#pragma unroll
    for (int i = 0; i < 4; i++)
#pragma unroll
      for (int j = 0; j < 4; j++)
        acc[i][j] = __builtin_amdgcn_mfma_f32_16x16x32_bf16(af[i], bf_[j], acc[i][j], 0, 0, 0);
    __syncthreads();
  }

  const int cr = (lane >> 4) * 4;
  const int cc = lane & 15;
#pragma unroll
  for (int j = 0; j < 4; j++) {
    const long col = bcol + wc + j * 16 + cc;
    if (col >= N) continue;
    const float bv = bias[col];
#pragma unroll
    for (int i = 0; i < 4; i++) {
#pragma unroll
      for (int r = 0; r < 4; r++) {
        const long row = brow + wr + i * 16 + cr + r;
        float v = acc[i][j][r] + bv;
        if constexpr (EPI == EP_RES)  v += residf[row * N + col];
        if constexpr (EPI == EP_RESB) v += __bfloat162float(residb[row * N + col]);
        if constexpr (EPI == EP_SILU) v = v / (1.f + __expf(-v));
        if constexpr (EPI == EP_MISH) {
          float t = __expf(fminf(v, 20.f));
          float u = (1.f + t); u *= u;
          v = v * (u - 1.f) / (u + 1.f);
        }
        if constexpr (OUTF) outf[row * N + col] = v;
        else                outb[row * N + col] = __float2bfloat16(v);
      }
    }
  }
}

// ---------------------------------------------------------------------------
__global__ __launch_bounds__(256)
void transpose_to_bf16(const float* __restrict__ W, bf16* __restrict__ Bt,
                       int K, int N, int Npad)
{
  __shared__ float tile[32][33];
  const int n0 = blockIdx.x * 32, k0 = blockIdx.y * 32;
  const int tx = threadIdx.x, ty = threadIdx.y;
  for (int r = ty; r < 32; r += 8) {
    int k = k0 + r, n = n0 + tx;
    tile[r][tx] = (k < K && n < N) ? W[(size_t)k * N + n] : 0.f;
  }
  __syncthreads();
  for (int r = ty; r < 32; r += 8) {
    int n = n0 + r, k = k0 + tx;
    if (n < Npad && k < K) Bt[(size_t)n * K + k] = __float2bfloat16(tile[tx][r]);
  }
}

__global__ __launch_bounds__(256)
void cvt_f32_bf16(const float* __restrict__ in, bf16* __restrict__ out, long n)
{
  long i = ((long)blockIdx.x * 256 + threadIdx.x) * 4;
  const long stride = (long)gridDim.x * 256 * 4;
  for (; i < n; i += stride) {
    float4 v = *(const float4*)(in + i);
    out[i]     = __float2bfloat16(v.x);
    out[i + 1] = __float2bfloat16(v.y);
    out[i + 2] = __float2bfloat16(v.z);
    out[i + 3] = __float2bfloat16(v.w);
  }
}

__global__ __launch_bounds__(256)
void pack3(const float* __restrict__ a, const float* __restrict__ b,
           const float* __restrict__ c, float* __restrict__ o, int n)
{
  int i = blockIdx.x * 256 + threadIdx.x;
  if (i < n) { o[i] = a[i]; o[n + i] = b[i]; o[2 * n + i] = c[i]; }
}

// ---------------------------------------------------------------------------
template<int ACT>
__global__ __launch_bounds__(256)
void ln_rows(const float* __restrict__ inf, const float* __restrict__ g,
             const float* __restrict__ be, bf16* __restrict__ ob, int C)
{
  const long row = blockIdx.x;
  float s = 0.f, ss = 0.f;
  for (int c = threadIdx.x; c < C; c += 256) {
    float v = inf[row * C + c];
    s += v; ss += v * v;
  }
#pragma unroll
  for (int o = 32; o; o >>= 1) { s += __shfl_xor(s, o); ss += __shfl_xor(ss, o); }
  __shared__ float p1[4], p2[4];
  const int wv = threadIdx.x >> 6;
  if ((threadIdx.x & 63) == 0) { p1[wv] = s; p2[wv] = ss; }
  __syncthreads();
  s  = p1[0] + p1[1] + p1[2] + p1[3];
  ss = p2[0] + p2[1] + p2[2] + p2[3];
  const float mean = s / C;
  const float var  = ss / C - mean * mean;
  const float rstd = rsqrtf(var + 1e-5f);
  for (int c = threadIdx.x; c < C; c += 256) {
    float v = (inf[row * C + c] - mean) * rstd * g[c] + be[c];
    if (ACT == 1) v = v / (1.f + __expf(-v));
    ob[row * C + c] = __float2bfloat16(v);
  }
}

template<bool WF, bool WB>
__global__ __launch_bounds__(256)
void ln1024(const bf16* __restrict__ inb, const float* __restrict__ g,
            const float* __restrict__ be, float* __restrict__ of,
            bf16* __restrict__ ob)
{
  const size_t row = blockIdx.x;
  const int t = threadIdx.x;
  const unsigned short* xr = (const unsigned short*)(inb + row * 1024) + t * 4;
  ushort4 raw = *(const ushort4*)xr;
  float v0 = bfu2f(raw.x), v1 = bfu2f(raw.y), v2 = bfu2f(raw.z), v3 = bfu2f(raw.w);
  float s = v0 + v1 + v2 + v3;
  float ss = v0 * v0 + v1 * v1 + v2 * v2 + v3 * v3;
#pragma unroll
  for (int o = 32; o; o >>= 1) { s += __shfl_xor(s, o); ss += __shfl_xor(ss, o); }
  __shared__ float p1[4], p2[4];
  const int wv = t >> 6;
  if ((t & 63) == 0) { p1[wv] = s; p2[wv] = ss; }
  __syncthreads();
  s  = p1[0] + p1[1] + p1[2] + p1[3];
  ss = p2[0] + p2[1] + p2[2] + p2[3];
  const float mean = s * (1.f / 1024.f);
  const float var  = ss * (1.f / 1024.f) - mean * mean;
  const float rstd = rsqrtf(var + 1e-5f);
  const int c = t * 4;
  float4 gg = *(const float4*)(g + c);
  float4 bb = *(const float4*)(be + c);
  float y0 = (v0 - mean) * rstd * gg.x + bb.x;
  float y1 = (v1 - mean) * rstd * gg.y + bb.y;
  float y2 = (v2 - mean) * rstd * gg.z + bb.z;
  float y3 = (v3 - mean) * rstd * gg.w + bb.w;
  if (WF) *(float4*)(of + row * 1024 + c) = make_float4(y0, y1, y2, y3);
  if (WB) {
    ushort4 o4 = { f2bfu(y0), f2bfu(y1), f2bfu(y2), f2bfu(y3) };
    *(ushort4*)((unsigned short*)(ob + row * 1024) + t * 4) = o4;
  }
}

// ---------------------------------------------------------------------------
// MFMA attention; smol row stride 6656 (padded).
// ---------------------------------------------------------------------------
__global__ __launch_bounds__(384)
void attn_mfma(const bf16* __restrict__ qkv, const bf16* __restrict__ smol,
               bf16* __restrict__ out)
{
  __shared__ char smem[37888];
  char* lqc = smem;
  char* lkc = smem + 12288;
  short* lvt = (short*)(smem + 24576);
  char* lpc = smem;

  const int b = blockIdx.x, h = blockIdx.y;
  const int tid = threadIdx.x;
  const int lane = tid & 63;
  const int w = tid >> 6;
  const int lr = lane & 15;
  const int kg = lane >> 4;

  const size_t qkv_base = (size_t)(b * 81) * 3072 + h * 64;

  for (int idx = tid; idx < 1296; idx += 384) {
    int which = idx >= 648;
    int e = which ? idx - 648 : idx;
    int s = e >> 3, c = e & 7;
    bf16x8 v = *(const bf16x8*)(qkv + qkv_base + (size_t)s * 3072 + which * 1024 + c * 8);
    char* base = which ? lkc : lqc;
    *(bf16x8*)(base + s * 128 + ((c ^ (s & 7)) << 4)) = v;
  }
  for (int idx = tid; idx < 648; idx += 384) {
    int s = idx >> 3, c = idx & 7;
    bf16x8 v = *(const bf16x8*)(qkv + qkv_base + (size_t)s * 3072 + 2048 + c * 8);
#pragma unroll
    for (int j = 0; j < 8; j++) lvt[(c * 8 + j) * 104 + s] = v[j];
  }
  {
    bf16x8 z = {};
    for (int idx = tid; idx < 240; idx += 384) {
      int which = idx >= 120;
      int e = which ? idx - 120 : idx;
      int s = 81 + (e >> 3), c = e & 7;
      char* base = which ? lkc : lqc;
      *(bf16x8*)(base + s * 128 + ((c ^ (s & 7)) << 4)) = z;
    }
    for (int idx = tid; idx < 1472; idx += 384) {
      int d = idx / 23, s = 81 + idx % 23;
      lvt[d * 104 + s] = 0;
    }
  }
  __syncthreads();

  f32x4 sacc[6] = {};
  const int m = w * 16 + lr;
#pragma unroll
  for (int ks = 0; ks < 2; ks++) {
    bf16x8 af = *(const bf16x8*)(lqc + m * 128 + ((((ks << 2) + kg) ^ (m & 7)) << 4));
#pragma unroll
    for (int j = 0; j < 6; j++) {
      int n = j * 16 + lr;
      bf16x8 bf_ = *(const bf16x8*)(lkc + n * 128 + ((((ks << 2) + kg) ^ (n & 7)) << 4));
      sacc[j] = __builtin_amdgcn_mfma_f32_16x16x32_bf16(af, bf_, sacc[j], 0, 0, 0);
    }
  }

  const bf16* smrow = smol + (size_t)(b * 16 + h) * 6656;
  float p[6][4];
#pragma unroll
  for (int j = 0; j < 6; j++) {
    int col = j * 16 + lr;
#pragma unroll
    for (int r = 0; r < 4; r++) {
      int row = w * 16 + kg * 4 + r;
      float sv = sacc[j][r] * 0.125f;
      if (col < 81) {
        if (row < 81) sv += __bfloat162float(smrow[row * 81 + col]);
      } else sv = -3.0e38f;
      p[j][r] = sv;
    }
  }
#pragma unroll
  for (int r = 0; r < 4; r++) {
    float mx = p[0][r];
#pragma unroll
    for (int j = 1; j < 6; j++) mx = fmaxf(mx, p[j][r]);
    mx = fmaxf(mx, __shfl_xor(mx, 1)); mx = fmaxf(mx, __shfl_xor(mx, 2));
    mx = fmaxf(mx, __shfl_xor(mx, 4)); mx = fmaxf(mx, __shfl_xor(mx, 8));
    float sum = 0.f;
#pragma unroll
    for (int j = 0; j < 6; j++) { float e = __expf(p[j][r] - mx); p[j][r] = e; sum += e; }
    sum += __shfl_xor(sum, 1); sum += __shfl_xor(sum, 2);
    sum += __shfl_xor(sum, 4); sum += __shfl_xor(sum, 8);
    float inv = 1.f / sum;
#pragma unroll
    for (int j = 0; j < 6; j++) p[j][r] *= inv;
  }
  __syncthreads();

#pragma unroll
  for (int j = 0; j < 6; j++) {
    int col = j * 16 + lr;
#pragma unroll
    for (int r = 0; r < 4; r++) {
      int row = w * 16 + kg * 4 + r;
      *(unsigned short*)(lpc + row * 256 + ((((col >> 3) ^ (row & 7)) << 4)) + (col & 7) * 2)
          = f2bfu(p[j][r]);
    }
  }
  __syncthreads();

  f32x4 oacc[4] = {};
#pragma unroll
  for (int ks = 0; ks < 3; ks++) {
    bf16x8 pa = *(const bf16x8*)(lpc + m * 256 + ((((ks << 2) + kg) ^ (m & 7)) << 4));
#pragma unroll
    for (int j2 = 0; j2 < 4; j2++) {
      int n = j2 * 16 + lr;
      bf16x8 vb = *(const bf16x8*)((char*)lvt + n * 208 + ((ks << 2) + kg) * 16);
      oacc[j2] = __builtin_amdgcn_mfma_f32_16x16x32_bf16(pa, vb, oacc[j2], 0, 0, 0);
    }
  }
#pragma unroll
  for (int j2 = 0; j2 < 4; j2++) {
    int d = j2 * 16 + lr;
#pragma unroll
    for (int r = 0; r < 4; r++) {
      int row = w * 16 + kg * 4 + r;
      if (row < 81)
        out[(size_t)(b * 81 + row) * 1024 + h * 64 + d] = __float2bfloat16(oacc[j2][r]);
    }
  }
}

// ---------------------------------------------------------------------------
extern "C" void kernel_launch(void* const* d_in, const int* in_sizes, int n_in,
                              void* d_out, int out_size, void* d_ws, size_t ws_size,
                              hipStream_t stream)
{
  const float* x     = (const float*)d_in[0];
  const float* w_c   = (const float*)d_in[1];
  const float* b_c   = (const float*)d_in[2];
  const float* w_d1  = (const float*)d_in[3];
  const float* b_d1  = (const float*)d_in[4];
  const float* ln1sg = (const float*)d_in[5];
  const float* ln1sb = (const float*)d_in[6];
  const float* w_d2  = (const float*)d_in[7];
  const float* b_d2  = (const float*)d_in[8];
  const float* ln2sg = (const float*)d_in[9];
  const float* ln2sb = (const float*)d_in[10];
  const float* w_gg  = (const float*)d_in[11];
  const float* b_gg  = (const float*)d_in[12];
  const float* wq    = (const float*)d_in[13];
  const float* bq    = (const float*)d_in[14];
  const float* wk    = (const float*)d_in[15];
  const float* bk    = (const float*)d_in[16];
  const float* wvp   = (const float*)d_in[17];
  const float* bv    = (const float*)d_in[18];
  const float* wo    = (const float*)d_in[19];
  const float* bo    = (const float*)d_in[20];
  const float* ln1g  = (const float*)d_in[21];
  const float* ln1b  = (const float*)d_in[22];
  const float* w_f1  = (const float*)d_in[23];
  const float* b_f1  = (const float*)d_in[24];
  const float* w_f2  = (const float*)d_in[25];
  const float* b_f2  = (const float*)d_in[26];
  const float* flng  = (const float*)d_in[27];
  const float* flnb  = (const float*)d_in[28];
  float* out = (float*)d_out;

  char* ws = (char*)d_ws;
  size_t off = 0;
  auto alloc = [&](size_t bytes) -> char* {
    char* p = ws + off; off += (bytes + 255) & ~(size_t)255; return p;
  };
  bf16*  Bt_c  = (bf16*)alloc(262144);      // 128x1024
  bf16*  Bt_d1 = (bf16*)alloc(1327104);     // 256x2592
  bf16*  Bt_d2 = (bf16*)alloc(2097152);     // 4096x256
  bf16*  Bt_gg = (bf16*)alloc(3407872);     // 6656x256
  bf16*  Bt_qkv= (bf16*)alloc(6291456);     // 3072x1024
  bf16*  Bt_wo = (bf16*)alloc(2097152);     // 1024x1024
  bf16*  Bt_f1 = (bf16*)alloc(8388608);     // 4096x1024
  bf16*  Bt_f2 = (bf16*)alloc(8388608);     // 1024x4096
  float* bqkv  = (float*)alloc(12288);
  bf16*  h0b   = (bf16*)alloc(2654208);     // 512x2592
  float* pre_s = (float*)alloc(8388608);
  bf16*  h1b   = (bf16*)alloc(262144);      // 512x256
  bf16*  h2b   = (bf16*)alloc(4194304);     // 8192x256
  char*  S1    = alloc(84934656);           // xb -> hmidb
  char*  S2    = alloc(339738624);          // qkvb+aob -> fb
  char*  S3    = alloc(109051904);          // smol(pad 6656) -> preln1 -> preln2

  bf16* xb     = (bf16*)S1;                 // live through wo (resid)
  bf16* hmidb  = (bf16*)S1;                 // after xb dead
  bf16* qkvb   = (bf16*)S2;                 // 41472x3072
  bf16* aob    = (bf16*)(S2 + 254803968);   // 41472x1024, after qkvb tail
  bf16* fb     = (bf16*)S2;                 // FFN intermediate (qkvb+aob dead)
  bf16* smol   = (bf16*)S3;                 // row stride 6656
  bf16* preln1 = (bf16*)S3;
  bf16* preln2 = (bf16*)S3;

  if (ws_size < off) { printf("WS too small: %zu < %zu\n", ws_size, off); return; }

  const dim3 tb(32, 8);
  transpose_to_bf16<<<dim3(4, 32),   tb, 0, stream>>>(w_c,  Bt_c,  1024, 32,   128);
  transpose_to_bf16<<<dim3(8, 81),   tb, 0, stream>>>(w_d1, Bt_d1, 2592, 256,  256);
  transpose_to_bf16<<<dim3(128, 8),  tb, 0, stream>>>(w_d2, Bt_d2, 256,  4096, 4096);
  transpose_to_bf16<<<dim3(208, 8),  tb, 0, stream>>>(w_gg, Bt_gg, 256,  6561, 6656);
  transpose_to_bf16<<<dim3(32, 32),  tb, 0, stream>>>(wq,   Bt_qkv,             1024, 1024, 1024);
  transpose_to_bf16<<<dim3(32, 32),  tb, 0, stream>>>(wk,   Bt_qkv + 1024*1024, 1024, 1024, 1024);
  transpose_to_bf16<<<dim3(32, 32),  tb, 0, stream>>>(wvp,  Bt_qkv + 2048*1024, 1024, 1024, 1024);
  transpose_to_bf16<<<dim3(32, 32),  tb, 0, stream>>>(wo,   Bt_wo, 1024, 1024, 1024);
  transpose_to_bf16<<<dim3(128, 32), tb, 0, stream>>>(w_f1, Bt_f1, 1024, 4096, 4096);
  transpose_to_bf16<<<dim3(32, 128), tb, 0, stream>>>(w_f2, Bt_f2, 4096, 1024, 1024);
  pack3<<<4, 256, 0, stream>>>(bq, bk, bv, bqkv, 1024);
  cvt_f32_bf16<<<2048, 256, 0, stream>>>(x, xb, 42467328L);

  // --- smolgen (small GEMMs on 128-tile kernel) ---
  gemm_kernel<EP_SILU, false><<<dim3(324, 1), 256, 0, stream>>>(
      xb, Bt_c, 41472, 32, 1024, b_c, nullptr, nullptr, nullptr, h0b);
  gemm_kernel<EP_NONE, true><<<dim3(4, 2), 256, 0, stream>>>(
      h0b, Bt_d1, 512, 256, 2592, b_d1, nullptr, nullptr, pre_s, nullptr);
  ln_rows<1><<<512, 256, 0, stream>>>(pre_s, ln1sg, ln1sb, h1b, 256);
  gemm_kernel<EP_NONE, true><<<dim3(4, 32), 256, 0, stream>>>(
      h1b, Bt_d2, 512, 4096, 256, b_d2, nullptr, nullptr, pre_s, nullptr);
  ln_rows<1><<<512, 256, 0, stream>>>(pre_s, ln2sg, ln2sb, h2b, 4096);
  gemm256<EP_NONE><<<32 * 26, 512, 0, stream>>>(
      h2b, Bt_gg, 6656, 6561, 256, 26, b_gg, nullptr, nullptr, smol);

  // --- attention ---
  gemm256<EP_NONE><<<162 * 12, 512, 0, stream>>>(
      xb, Bt_qkv, 3072, 3072, 1024, 12, bqkv, nullptr, nullptr, qkvb);
  attn_mfma<<<dim3(512, 16), 384, 0, stream>>>(qkvb, smol, aob);
  gemm256<EP_RESB><<<162 * 4, 512, 0, stream>>>(
      aob, Bt_wo, 1024, 1024, 1024, 4, bo, nullptr, xb, preln1);
  ln1024<false, true><<<41472, 256, 0, stream>>>(preln1, ln1g, ln1b, nullptr, hmidb);

  // --- FFN ---
  gemm256<EP_MISH><<<162 * 16, 512, 0, stream>>>(
      hmidb, Bt_f1, 4096, 4096, 1024, 16, b_f1, nullptr, nullptr, fb);
  gemm256<EP_RESB><<<162 * 4, 512, 0, stream>>>(
      fb, Bt_f2, 1024, 1024, 4096, 4, b_f2, nullptr, hmidb, preln2);
  ln1024<true, false><<<41472, 256, 0, stream>>>(preln2, flng, flnb, out, nullptr);
}

// Round 14
// 1654.869 us; speedup vs baseline: 1.0882x; 1.0882x over previous
//
#include <hip/hip_runtime.h>
#include <hip/hip_bf16.h>
#include <cstdint>
#include <cstdio>

using bf16 = __hip_bfloat16;
typedef __attribute__((ext_vector_type(8))) short bf16x8;
typedef __attribute__((ext_vector_type(4))) float f32x4;

__device__ __forceinline__ void gload_lds16(const void* g, void* l) {
  __builtin_amdgcn_global_load_lds((__attribute__((address_space(1))) void*)g,
                                   (__attribute__((address_space(3))) void*)l,
                                   16, 0, 0);
}

__device__ __forceinline__ float bfu2f(unsigned short u) {
  return __uint_as_float((unsigned int)u << 16);
}
__device__ __forceinline__ unsigned short f2bfu(float f) {
  bf16 b = __float2bfloat16(f);
  return *(unsigned short*)&b;
}

enum { EP_NONE = 0, EP_SILU = 1, EP_MISH = 2, EP_RES = 3, EP_RESB = 4 };

// ---------------------------------------------------------------------------
// 256x256-tile quad-phase bf16 MFMA GEMM (r12 config — best measured; r13's
// 32x32 shape regressed, reverted). Phase = one 128x128 C-quadrant, quad
// order (A0B0),(A0B1),(A1B1),(A1B0); vmcnt(6) once per K-tile; 1 barrier per
// phase; 16B-chunk swizzle (0 conflicts measured). 680 TF structural floor
// for K~1024 shapes — 7 falsified alternatives (r8-r13), do not restructure.
// Requires: M%256==0, N%256==0 (stride), K%64==0, K/64>=3.
// ---------------------------------------------------------------------------
template<int EPI>
__global__ __launch_bounds__(512, 1)
void gemm256(const bf16* __restrict__ A, const bf16* __restrict__ Bt,
             int N, int Nb, int K, int gy,
             const float* __restrict__ bias,
             const float* __restrict__ residf,
             const bf16* __restrict__ residb,
             bf16* __restrict__ outb)
{
  __shared__ char lds[131072];
  const int tid  = threadIdx.x;
  const int lane = tid & 63;
  const int wid  = tid >> 6;
  const int wm = wid >> 2, wn = wid & 3;     // 2 x 4 waves per quadrant
  const int lr = lane & 15, kg = lane >> 4;

  // bijective XCD-chunked remap; bx-major (r10: lowest HBM traffic)
  const int nwg = gridDim.x;
  const int q8 = nwg >> 3, r8 = nwg & 7;
  const int xcd = blockIdx.x & 7, idx = blockIdx.x >> 3;
  const int wg2 = (xcd < r8 ? xcd * (q8 + 1) : r8 * (q8 + 1) + (xcd - r8) * q8) + idx;
  const int bx = wg2 / gy, by = wg2 % gy;
  const long brow = (long)bx * 256, bcol = (long)by * 256;

  const size_t rb = (size_t)K * 2;                   // bytes per row
  const int srow8 = wid * 8 + (lane >> 3);           // staging row in 64-block
  const int coff  = ((lane & 7) ^ (lane >> 3)) << 4; // pre-swizzled chunk
  const char* aS = (const char*)A  + (size_t)(brow + srow8) * rb + coff;
  const char* bS = (const char*)Bt + (size_t)(bcol + srow8) * rb + coff;
  char* ldsA = lds;
  char* ldsB = lds + 65536;
  const int luni = wid * 1024;

  const int kt = K >> 6;

  auto stA = [&](int t, int h) {
    const char* s = aS + (size_t)(h * 128) * rb + (size_t)t * 128;
    char* d = ldsA + (t & 1) * 32768 + h * 16384 + luni;
    gload_lds16(s, d);
    gload_lds16(s + (size_t)64 * rb, d + 8192);
  };
  auto stB = [&](int t, int h) {
    const char* s = bS + (size_t)(h * 128) * rb + (size_t)t * 128;
    char* d = ldsB + (t & 1) * 32768 + h * 16384 + luni;
    gload_lds16(s, d);
    gload_lds16(s + (size_t)64 * rb, d + 8192);
  };

  f32x4 acc[4][4][2] = {};     // [quad][i][j]
  bf16x8 afr[4][2], bfr[2][2]; // [i][ks], [j][ks]

  // prologue: 7 half-tiles in steady-state-compatible issue order
  stA(0, 0); stB(0, 0); stB(0, 1); stA(0, 1);
  stA(1, 0); stB(1, 1); stA(1, 1);

  const int swz  = lr & 7;
  const int arow = wm * 64 + lr;   // + i*16, within 128-row half
  const int brw  = wn * 32 + lr;   // + j*16, within 128-row half

#define KCH(ks) ((((((ks) << 2) + kg) ^ swz)) << 4)
#define RD_A(rh) \
  _Pragma("unroll") for (int i = 0; i < 4; i++) \
  _Pragma("unroll") for (int ks = 0; ks < 2; ks++) \
    afr[i][ks] = *(const bf16x8*)(pA + (rh) * 16384 + (arow + i * 16) * 128 + KCH(ks));
#define RD_B(ch) \
  _Pragma("unroll") for (int j = 0; j < 2; j++) \
  _Pragma("unroll") for (int ks = 0; ks < 2; ks++) \
    bfr[j][ks] = *(const bf16x8*)(pB + (ch) * 16384 + (brw + j * 16) * 128 + KCH(ks));
#define MFMA_Q(q) \
  asm volatile("s_waitcnt lgkmcnt(0)" ::: "memory"); \
  __builtin_amdgcn_sched_barrier(0); \
  __builtin_amdgcn_s_setprio(1); \
  _Pragma("unroll") for (int i = 0; i < 4; i++) \
  _Pragma("unroll") for (int j = 0; j < 2; j++) \
  _Pragma("unroll") for (int ks = 0; ks < 2; ks++) \
    acc[q][i][j] = __builtin_amdgcn_mfma_f32_16x16x32_bf16(afr[i][ks], bfr[j][ks], acc[q][i][j], 0, 0, 0); \
  __builtin_amdgcn_s_setprio(0);

  for (int t = 0; t < kt; ++t) {
    const char* pA = ldsA + (t & 1) * 32768;
    const char* pB = ldsB + (t & 1) * 32768;

    // ---- ph0: quad (A0,B0) ----
    if (t + 1 < kt) asm volatile("s_waitcnt vmcnt(6)" ::: "memory");
    else            asm volatile("s_waitcnt vmcnt(0)" ::: "memory");
    __builtin_amdgcn_s_barrier();
    RD_A(0) RD_B(0)
    if (t + 1 < kt) stB(t + 1, 0);
    MFMA_Q(0)

    // ---- ph1: quad (A0,B1) — reuse afr ----
    __builtin_amdgcn_s_barrier();
    RD_B(1)
    if (t + 2 < kt) stA(t + 2, 0);
    MFMA_Q(1)

    // ---- ph2: quad (A1,B1) — reuse bfr ----
    __builtin_amdgcn_s_barrier();
    RD_A(1)
    if (t + 2 < kt) stB(t + 2, 1);
    MFMA_Q(2)

    // ---- ph3: quad (A1,B0) — reuse afr, re-read B0 ----
    __builtin_amdgcn_s_barrier();
    RD_B(0)
    if (t + 2 < kt) stA(t + 2, 1);
    MFMA_Q(3)
  }
#undef KCH
#undef RD_A
#undef RD_B
#undef MFMA_Q

  __syncthreads();

  // ---- epilogue: bias(+act) -> LDS (swizzled) -> coalesced bf16x8 stores ----
  char* lC = lds;
#pragma unroll
  for (int q = 0; q < 4; q++) {
    const int rh = (q >= 2), ch = (q == 1 || q == 2);
#pragma unroll
    for (int j = 0; j < 2; j++) {
      const int tcol = ch * 128 + wn * 32 + j * 16 + lr;
      const long gcol = bcol + tcol;
      const float bv = (gcol < Nb) ? bias[gcol] : 0.f;
#pragma unroll
      for (int i = 0; i < 4; i++) {
#pragma unroll
        for (int r = 0; r < 4; r++) {
          const int row = rh * 128 + wm * 64 + i * 16 + kg * 4 + r;
          float v = acc[q][i][j][r] + bv;
          if constexpr (EPI == EP_MISH) {
            float e = __expf(fminf(v, 20.f));
            float u = (1.f + e); u *= u;
            v = v * (u - 1.f) / (u + 1.f);
          }
          *(unsigned short*)(lC + row * 512 + ((tcol * 2) ^ ((row & 12) << 3))) = f2bfu(v);
        }
      }
    }
  }
  __syncthreads();
  const int trow = tid >> 5;
  const int tcb  = (tid & 31) * 16;
#pragma unroll
  for (int it = 0; it < 16; ++it) {
    const int row = it * 16 + trow;
    bf16x8 vv = *(const bf16x8*)(lC + row * 512 + (tcb ^ ((row & 12) << 3)));
    const long grow = brow + row;
    bf16* dst = outb + grow * (long)N + bcol + (tcb >> 1);
    if constexpr (EPI == EP_RES) {
      const float* rs = residf + grow * (long)N + bcol + (tcb >> 1);
      float4 ra = *(const float4*)rs, rb2 = *(const float4*)(rs + 4);
      float rv[8] = {ra.x, ra.y, ra.z, ra.w, rb2.x, rb2.y, rb2.z, rb2.w};
      bf16x8 ov;
#pragma unroll
      for (int e = 0; e < 8; e++)
        ov[e] = (short)f2bfu(bfu2f((unsigned short)vv[e]) + rv[e]);
      *(bf16x8*)dst = ov;
    } else if constexpr (EPI == EP_RESB) {
      bf16x8 rb3 = *(const bf16x8*)(residb + grow * (long)N + bcol + (tcb >> 1));
      bf16x8 ov;
#pragma unroll
      for (int e = 0; e < 8; e++)
        ov[e] = (short)f2bfu(bfu2f((unsigned short)vv[e]) + bfu2f((unsigned short)rb3[e]));
      *(bf16x8*)dst = ov;
    } else {
      *(bf16x8*)dst = vv;
    }
  }
}

// ---------------------------------------------------------------------------
// 128x128-tile bf16 MFMA GEMM (m97 structure) — small smolgen GEMMs.
// ---------------------------------------------------------------------------
template<int EPI, bool OUTF>
__global__ __launch_bounds__(256)
void gemm_kernel(const bf16* __restrict__ A, const bf16* __restrict__ Bt,
                 int M, int N, int K,
                 const float* __restrict__ bias,
                 const float* __restrict__ residf,
                 const bf16* __restrict__ residb,
                 float* __restrict__ outf, bf16* __restrict__ outb)
{
  __shared__ bf16 lA[128 * 32];
  __shared__ bf16 lB[128 * 32];
  const int tid  = threadIdx.x;
  const int lane = tid & 63;
  const int wvid = tid >> 6;
  const int wr = (wvid >> 1) * 64;
  const int wc = (wvid & 1) * 64;
  const long brow = (long)blockIdx.x * 128;
  const long bcol = (long)blockIdx.y * 128;
  const int lr = lane & 15;
  const int k8 = (lane >> 4) * 8;

  const int lofs0 = wvid * 1024;
  const int lofs1 = lofs0 + 4096;
  const int o0 = lofs0 + lane * 16;
  const int o1 = o0 + 4096;
  const int r0 = o0 >> 6, c0 = o0 & 63;
  const int r1 = o1 >> 6, c1 = o1 & 63;

  f32x4 acc[4][4] = {};

  for (int k0 = 0; k0 < K; k0 += 32) {
    const long kb = (long)k0 * 2;
    gload_lds16((const char*)A  + ((brow + r0) * (long)K) * 2 + kb + c0, (char*)lA + lofs0);
    gload_lds16((const char*)A  + ((brow + r1) * (long)K) * 2 + kb + c1, (char*)lA + lofs1);
    gload_lds16((const char*)Bt + ((bcol + r0) * (long)K) * 2 + kb + c0, (char*)lB + lofs0);
    gload_lds16((const char*)Bt + ((bcol + r1) * (long)K) * 2 + kb + c1, (char*)lB + lofs1);
    __syncthreads();
    bf16x8 af[4], bf_[4];
#pragma unroll
    for (int i = 0; i < 4; i++)
      af[i] = *(const bf16x8*)&lA[(wr + i * 16 + lr) * 32 + k8];
#pragma unroll
    for (int j = 0; j < 4; j++)
      bf_[j] = *(const bf16x8*)&lB[(wc + j * 16 + lr) * 32 + k8];
#pragma unroll
    for (int i = 0; i < 4; i++)
#pragma unroll
      for (int j = 0; j < 4; j++)
        acc[i][j] = __builtin_amdgcn_mfma_f32_16x16x32_bf16(af[i], bf_[j], acc[i][j], 0, 0, 0);
    __syncthreads();
  }

  const int cr = (lane >> 4) * 4;
  const int cc = lane & 15;
#pragma unroll
  for (int j = 0; j < 4; j++) {
    const long col = bcol + wc + j * 16 + cc;
    if (col >= N) continue;
    const float bv = bias[col];
#pragma unroll
    for (int i = 0; i < 4; i++) {
#pragma unroll
      for (int r = 0; r < 4; r++) {
        const long row = brow + wr + i * 16 + cr + r;
        float v = acc[i][j][r] + bv;
        if constexpr (EPI == EP_RES)  v += residf[row * N + col];
        if constexpr (EPI == EP_RESB) v += __bfloat162float(residb[row * N + col]);
        if constexpr (EPI == EP_SILU) v = v / (1.f + __expf(-v));
        if constexpr (EPI == EP_MISH) {
          float t = __expf(fminf(v, 20.f));
          float u = (1.f + t); u *= u;
          v = v * (u - 1.f) / (u + 1.f);
        }
        if constexpr (OUTF) outf[row * N + col] = v;
        else                outb[row * N + col] = __float2bfloat16(v);
      }
    }
  }
}

// ---------------------------------------------------------------------------
// Split-K 128x128 GEMM partial: atomicAdd fp32 into pre-zeroed outf.
// Grid (mx, ny, S); slice z covers K rows [z*KS, (z+1)*KS), KS%32==0.
// Slice 0 adds bias. Used for smolgen d1 (512x256 @K2592: 8 -> 72 blocks).
// ---------------------------------------------------------------------------
__global__ __launch_bounds__(256)
void gemm_splitk(const bf16* __restrict__ A, const bf16* __restrict__ Bt,
                 int M, int N, int K, int KS,
                 const float* __restrict__ bias, float* __restrict__ outf)
{
  __shared__ bf16 lA[128 * 32];
  __shared__ bf16 lB[128 * 32];
  const int tid  = threadIdx.x;
  const int lane = tid & 63;
  const int wvid = tid >> 6;
  const int wr = (wvid >> 1) * 64;
  const int wc = (wvid & 1) * 64;
  const long brow = (long)blockIdx.x * 128;
  const long bcol = (long)blockIdx.y * 128;
  const int kz = blockIdx.z;
  const int lr = lane & 15;
  const int k8 = (lane >> 4) * 8;

  const int lofs0 = wvid * 1024;
  const int lofs1 = lofs0 + 4096;
  const int o0 = lofs0 + lane * 16;
  const int o1 = o0 + 4096;
  const int r0 = o0 >> 6, c0 = o0 & 63;
  const int r1 = o1 >> 6, c1 = o1 & 63;

  f32x4 acc[4][4] = {};

  const int kbeg = kz * KS, kend = kbeg + KS;
  for (int k0 = kbeg; k0 < kend; k0 += 32) {
    const long kb = (long)k0 * 2;
    gload_lds16((const char*)A  + ((brow + r0) * (long)K) * 2 + kb + c0, (char*)lA + lofs0);
    gload_lds16((const char*)A  + ((brow + r1) * (long)K) * 2 + kb + c1, (char*)lA + lofs1);
    gload_lds16((const char*)Bt + ((bcol + r0) * (long)K) * 2 + kb + c0, (char*)lB + lofs0);
    gload_lds16((const char*)Bt + ((bcol + r1) * (long)K) * 2 + kb + c1, (char*)lB + lofs1);
    __syncthreads();
    bf16x8 af[4], bf_[4];
#pragma unroll
    for (int i = 0; i < 4; i++)
      af[i] = *(const bf16x8*)&lA[(wr + i * 16 + lr) * 32 + k8];
#pragma unroll
    for (int j = 0; j < 4; j++)
      bf_[j] = *(const bf16x8*)&lB[(wc + j * 16 + lr) * 32 + k8];
#pragma unroll
    for (int i = 0; i < 4; i++)
#pragma unroll
      for (int j = 0; j < 4; j++)
        acc[i][j] = __builtin_amdgcn_mfma_f32_16x16x32_bf16(af[i], bf_[j], acc[i][j], 0, 0, 0);
    __syncthreads();
  }

  const int cr = (lane >> 4) * 4;
  const int cc = lane & 15;
#pragma unroll
  for (int j = 0; j < 4; j++) {
    const long col = bcol + wc + j * 16 + cc;
    if (col >= N) continue;
    const float bv = (kz == 0) ? bias[col] : 0.f;
#pragma unroll
    for (int i = 0; i < 4; i++) {
#pragma unroll
      for (int r = 0; r < 4; r++) {
        const long row = brow + wr + i * 16 + cr + r;
        if (row < M) atomicAdd(&outf[row * N + col], acc[i][j][r] + bv);
      }
    }
  }
}

__global__ __launch_bounds__(256)
void zero_f32(float* __restrict__ p, long n)
{
  long i = (long)blockIdx.x * 256 + threadIdx.x;
  if (i < n) p[i] = 0.f;
}

// ---------------------------------------------------------------------------
__global__ __launch_bounds__(256)
void transpose_to_bf16(const float* __restrict__ W, bf16* __restrict__ Bt,
                       int K, int N, int Npad)
{
  __shared__ float tile[32][33];
  const int n0 = blockIdx.x * 32, k0 = blockIdx.y * 32;
  const int tx = threadIdx.x, ty = threadIdx.y;
  for (int r = ty; r < 32; r += 8) {
    int k = k0 + r, n = n0 + tx;
    tile[r][tx] = (k < K && n < N) ? W[(size_t)k * N + n] : 0.f;
  }
  __syncthreads();
  for (int r = ty; r < 32; r += 8) {
    int n = n0 + r, k = k0 + tx;
    if (n < Npad && k < K) Bt[(size_t)n * K + k] = __float2bfloat16(tile[tx][r]);
  }
}

__global__ __launch_bounds__(256)
void cvt_f32_bf16(const float* __restrict__ in, bf16* __restrict__ out, long n)
{
  long i = ((long)blockIdx.x * 256 + threadIdx.x) * 4;
  const long stride = (long)gridDim.x * 256 * 4;
  for (; i < n; i += stride) {
    float4 v = *(const float4*)(in + i);
    out[i]     = __float2bfloat16(v.x);
    out[i + 1] = __float2bfloat16(v.y);
    out[i + 2] = __float2bfloat16(v.z);
    out[i + 3] = __float2bfloat16(v.w);
  }
}

__global__ __launch_bounds__(256)
void pack3(const float* __restrict__ a, const float* __restrict__ b,
           const float* __restrict__ c, float* __restrict__ o, int n)
{
  int i = blockIdx.x * 256 + threadIdx.x;
  if (i < n) { o[i] = a[i]; o[n + i] = b[i]; o[2 * n + i] = c[i]; }
}

// ---------------------------------------------------------------------------
template<int ACT>
__global__ __launch_bounds__(256)
void ln_rows(const float* __restrict__ inf, const float* __restrict__ g,
             const float* __restrict__ be, bf16* __restrict__ ob, int C)
{
  const long row = blockIdx.x;
  float s = 0.f, ss = 0.f;
  for (int c = threadIdx.x; c < C; c += 256) {
    float v = inf[row * C + c];
    s += v; ss += v * v;
  }
#pragma unroll
  for (int o = 32; o; o >>= 1) { s += __shfl_xor(s, o); ss += __shfl_xor(ss, o); }
  __shared__ float p1[4], p2[4];
  const int wv = threadIdx.x >> 6;
  if ((threadIdx.x & 63) == 0) { p1[wv] = s; p2[wv] = ss; }
  __syncthreads();
  s  = p1[0] + p1[1] + p1[2] + p1[3];
  ss = p2[0] + p2[1] + p2[2] + p2[3];
  const float mean = s / C;
  const float var  = ss / C - mean * mean;
  const float rstd = rsqrtf(var + 1e-5f);
  for (int c = threadIdx.x; c < C; c += 256) {
    float v = (inf[row * C + c] - mean) * rstd * g[c] + be[c];
    if (ACT == 1) v = v / (1.f + __expf(-v));
    ob[row * C + c] = __float2bfloat16(v);
  }
}

template<bool WF, bool WB>
__global__ __launch_bounds__(256)
void ln1024(const bf16* __restrict__ inb, const float* __restrict__ g,
            const float* __restrict__ be, float* __restrict__ of,
            bf16* __restrict__ ob)
{
  const size_t row = blockIdx.x;
  const int t = threadIdx.x;
  const unsigned short* xr = (const unsigned short*)(inb + row * 1024) + t * 4;
  ushort4 raw = *(const ushort4*)xr;
  float v0 = bfu2f(raw.x), v1 = bfu2f(raw.y), v2 = bfu2f(raw.z), v3 = bfu2f(raw.w);
  float s = v0 + v1 + v2 + v3;
  float ss = v0 * v0 + v1 * v1 + v2 * v2 + v3 * v3;
#pragma unroll
  for (int o = 32; o; o >>= 1) { s += __shfl_xor(s, o); ss += __shfl_xor(ss, o); }
  __shared__ float p1[4], p2[4];
  const int wv = t >> 6;
  if ((t & 63) == 0) { p1[wv] = s; p2[wv] = ss; }
  __syncthreads();
  s  = p1[0] + p1[1] + p1[2] + p1[3];
  ss = p2[0] + p2[1] + p2[2] + p2[3];
  const float mean = s * (1.f / 1024.f);
  const float var  = ss * (1.f / 1024.f) - mean * mean;
  const float rstd = rsqrtf(var + 1e-5f);
  const int c = t * 4;
  float4 gg = *(const float4*)(g + c);
  float4 bb = *(const float4*)(be + c);
  float y0 = (v0 - mean) * rstd * gg.x + bb.x;
  float y1 = (v1 - mean) * rstd * gg.y + bb.y;
  float y2 = (v2 - mean) * rstd * gg.z + bb.z;
  float y3 = (v3 - mean) * rstd * gg.w + bb.w;
  if (WF) *(float4*)(of + row * 1024 + c) = make_float4(y0, y1, y2, y3);
  if (WB) {
    ushort4 o4 = { f2bfu(y0), f2bfu(y1), f2bfu(y2), f2bfu(y3) };
    *(ushort4*)((unsigned short*)(ob + row * 1024) + t * 4) = o4;
  }
}

// ---------------------------------------------------------------------------
// MFMA attention; smol row stride 6656 (padded).
// ---------------------------------------------------------------------------
__global__ __launch_bounds__(384)
void attn_mfma(const bf16* __restrict__ qkv, const bf16* __restrict__ smol,
               bf16* __restrict__ out)
{
  __shared__ char smem[37888];
  char* lqc = smem;
  char* lkc = smem + 12288;
  short* lvt = (short*)(smem + 24576);
  char* lpc = smem;

  const int b = blockIdx.x, h = blockIdx.y;
  const int tid = threadIdx.x;
  const int lane = tid & 63;
  const int w = tid >> 6;
  const int lr = lane & 15;
  const int kg = lane >> 4;

  const size_t qkv_base = (size_t)(b * 81) * 3072 + h * 64;

  for (int idx = tid; idx < 1296; idx += 384) {
    int which = idx >= 648;
    int e = which ? idx - 648 : idx;
    int s = e >> 3, c = e & 7;
    bf16x8 v = *(const bf16x8*)(qkv + qkv_base + (size_t)s * 3072 + which * 1024 + c * 8);
    char* base = which ? lkc : lqc;
    *(bf16x8*)(base + s * 128 + ((c ^ (s & 7)) << 4)) = v;
  }
  for (int idx = tid; idx < 648; idx += 384) {
    int s = idx >> 3, c = idx & 7;
    bf16x8 v = *(const bf16x8*)(qkv + qkv_base + (size_t)s * 3072 + 2048 + c * 8);
#pragma unroll
    for (int j = 0; j < 8; j++) lvt[(c * 8 + j) * 104 + s] = v[j];
  }
  {
    bf16x8 z = {};
    for (int idx = tid; idx < 240; idx += 384) {
      int which = idx >= 120;
      int e = which ? idx - 120 : idx;
      int s = 81 + (e >> 3), c = e & 7;
      char* base = which ? lkc : lqc;
      *(bf16x8*)(base + s * 128 + ((c ^ (s & 7)) << 4)) = z;
    }
    for (int idx = tid; idx < 1472; idx += 384) {
      int d = idx / 23, s = 81 + idx % 23;
      lvt[d * 104 + s] = 0;
    }
  }
  __syncthreads();

  f32x4 sacc[6] = {};
  const int m = w * 16 + lr;
#pragma unroll
  for (int ks = 0; ks < 2; ks++) {
    bf16x8 af = *(const bf16x8*)(lqc + m * 128 + ((((ks << 2) + kg) ^ (m & 7)) << 4));
#pragma unroll
    for (int j = 0; j < 6; j++) {
      int n = j * 16 + lr;
      bf16x8 bf_ = *(const bf16x8*)(lkc + n * 128 + ((((ks << 2) + kg) ^ (n & 7)) << 4));
      sacc[j] = __builtin_amdgcn_mfma_f32_16x16x32_bf16(af, bf_, sacc[j], 0, 0, 0);
    }
  }

  const bf16* smrow = smol + (size_t)(b * 16 + h) * 6656;
  float p[6][4];
#pragma unroll
  for (int j = 0; j < 6; j++) {
    int col = j * 16 + lr;
#pragma unroll
    for (int r = 0; r < 4; r++) {
      int row = w * 16 + kg * 4 + r;
      float sv = sacc[j][r] * 0.125f;
      if (col < 81) {
        if (row < 81) sv += __bfloat162float(smrow[row * 81 + col]);
      } else sv = -3.0e38f;
      p[j][r] = sv;
    }
  }
#pragma unroll
  for (int r = 0; r < 4; r++) {
    float mx = p[0][r];
#pragma unroll
    for (int j = 1; j < 6; j++) mx = fmaxf(mx, p[j][r]);
    mx = fmaxf(mx, __shfl_xor(mx, 1)); mx = fmaxf(mx, __shfl_xor(mx, 2));
    mx = fmaxf(mx, __shfl_xor(mx, 4)); mx = fmaxf(mx, __shfl_xor(mx, 8));
    float sum = 0.f;
#pragma unroll
    for (int j = 0; j < 6; j++) { float e = __expf(p[j][r] - mx); p[j][r] = e; sum += e; }
    sum += __shfl_xor(sum, 1); sum += __shfl_xor(sum, 2);
    sum += __shfl_xor(sum, 4); sum += __shfl_xor(sum, 8);
    float inv = 1.f / sum;
#pragma unroll
    for (int j = 0; j < 6; j++) p[j][r] *= inv;
  }
  __syncthreads();

#pragma unroll
  for (int j = 0; j < 6; j++) {
    int col = j * 16 + lr;
#pragma unroll
    for (int r = 0; r < 4; r++) {
      int row = w * 16 + kg * 4 + r;
      *(unsigned short*)(lpc + row * 256 + ((((col >> 3) ^ (row & 7)) << 4)) + (col & 7) * 2)
          = f2bfu(p[j][r]);
    }
  }
  __syncthreads();

  f32x4 oacc[4] = {};
#pragma unroll
  for (int ks = 0; ks < 3; ks++) {
    bf16x8 pa = *(const bf16x8*)(lpc + m * 256 + ((((ks << 2) + kg) ^ (m & 7)) << 4));
#pragma unroll
    for (int j2 = 0; j2 < 4; j2++) {
      int n = j2 * 16 + lr;
      bf16x8 vb = *(const bf16x8*)((char*)lvt + n * 208 + ((ks << 2) + kg) * 16);
      oacc[j2] = __builtin_amdgcn_mfma_f32_16x16x32_bf16(pa, vb, oacc[j2], 0, 0, 0);
    }
  }
#pragma unroll
  for (int j2 = 0; j2 < 4; j2++) {
    int d = j2 * 16 + lr;
#pragma unroll
    for (int r = 0; r < 4; r++) {
      int row = w * 16 + kg * 4 + r;
      if (row < 81)
        out[(size_t)(b * 81 + row) * 1024 + h * 64 + d] = __float2bfloat16(oacc[j2][r]);
    }
  }
}

// ---------------------------------------------------------------------------
extern "C" void kernel_launch(void* const* d_in, const int* in_sizes, int n_in,
                              void* d_out, int out_size, void* d_ws, size_t ws_size,
                              hipStream_t stream)
{
  const float* x     = (const float*)d_in[0];
  const float* w_c   = (const float*)d_in[1];
  const float* b_c   = (const float*)d_in[2];
  const float* w_d1  = (const float*)d_in[3];
  const float* b_d1  = (const float*)d_in[4];
  const float* ln1sg = (const float*)d_in[5];
  const float* ln1sb = (const float*)d_in[6];
  const float* w_d2  = (const float*)d_in[7];
  const float* b_d2  = (const float*)d_in[8];
  const float* ln2sg = (const float*)d_in[9];
  const float* ln2sb = (const float*)d_in[10];
  const float* w_gg  = (const float*)d_in[11];
  const float* b_gg  = (const float*)d_in[12];
  const float* wq    = (const float*)d_in[13];
  const float* bq    = (const float*)d_in[14];
  const float* wk    = (const float*)d_in[15];
  const float* bk    = (const float*)d_in[16];
  const float* wvp   = (const float*)d_in[17];
  const float* bv    = (const float*)d_in[18];
  const float* wo    = (const float*)d_in[19];
  const float* bo    = (const float*)d_in[20];
  const float* ln1g  = (const float*)d_in[21];
  const float* ln1b  = (const float*)d_in[22];
  const float* w_f1  = (const float*)d_in[23];
  const float* b_f1  = (const float*)d_in[24];
  const float* w_f2  = (const float*)d_in[25];
  const float* b_f2  = (const float*)d_in[26];
  const float* flng  = (const float*)d_in[27];
  const float* flnb  = (const float*)d_in[28];
  float* out = (float*)d_out;

  char* ws = (char*)d_ws;
  size_t off = 0;
  auto alloc = [&](size_t bytes) -> char* {
    char* p = ws + off; off += (bytes + 255) & ~(size_t)255; return p;
  };
  bf16*  Bt_c  = (bf16*)alloc(262144);      // 128x1024
  bf16*  Bt_d1 = (bf16*)alloc(1327104);     // 256x2592
  bf16*  Bt_d2 = (bf16*)alloc(2097152);     // 4096x256
  bf16*  Bt_gg = (bf16*)alloc(3407872);     // 6656x256
  bf16*  Bt_qkv= (bf16*)alloc(6291456);     // 3072x1024
  bf16*  Bt_wo = (bf16*)alloc(2097152);     // 1024x1024
  bf16*  Bt_f1 = (bf16*)alloc(8388608);     // 4096x1024
  bf16*  Bt_f2 = (bf16*)alloc(8388608);     // 1024x4096
  float* bqkv  = (float*)alloc(12288);
  bf16*  h0b   = (bf16*)alloc(2654208);     // 512x2592
  float* pre_s = (float*)alloc(8388608);
  bf16*  h1b   = (bf16*)alloc(262144);      // 512x256
  bf16*  h2b   = (bf16*)alloc(4194304);     // 8192x256
  char*  S1    = alloc(84934656);           // xb -> hmidb
  char*  S2    = alloc(339738624);          // qkvb+aob -> fb
  char*  S3    = alloc(109051904);          // smol(pad 6656) -> preln1 -> preln2

  bf16* xb     = (bf16*)S1;                 // live through wo (resid)
  bf16* hmidb  = (bf16*)S1;                 // after xb dead
  bf16* qkvb   = (bf16*)S2;                 // 41472x3072
  bf16* aob    = (bf16*)(S2 + 254803968);   // 41472x1024, after qkvb tail
  bf16* fb     = (bf16*)S2;                 // FFN intermediate (qkvb+aob dead)
  bf16* smol   = (bf16*)S3;                 // row stride 6656
  bf16* preln1 = (bf16*)S3;
  bf16* preln2 = (bf16*)S3;

  if (ws_size < off) { printf("WS too small: %zu < %zu\n", ws_size, off); return; }

  const dim3 tb(32, 8);
  transpose_to_bf16<<<dim3(4, 32),   tb, 0, stream>>>(w_c,  Bt_c,  1024, 32,   128);
  transpose_to_bf16<<<dim3(8, 81),   tb, 0, stream>>>(w_d1, Bt_d1, 2592, 256,  256);
  transpose_to_bf16<<<dim3(128, 8),  tb, 0, stream>>>(w_d2, Bt_d2, 256,  4096, 4096);
  transpose_to_bf16<<<dim3(208, 8),  tb, 0, stream>>>(w_gg, Bt_gg, 256,  6561, 6656);
  transpose_to_bf16<<<dim3(32, 32),  tb, 0, stream>>>(wq,   Bt_qkv,             1024, 1024, 1024);
  transpose_to_bf16<<<dim3(32, 32),  tb, 0, stream>>>(wk,   Bt_qkv + 1024*1024, 1024, 1024, 1024);
  transpose_to_bf16<<<dim3(32, 32),  tb, 0, stream>>>(wvp,  Bt_qkv + 2048*1024, 1024, 1024, 1024);
  transpose_to_bf16<<<dim3(32, 32),  tb, 0, stream>>>(wo,   Bt_wo, 1024, 1024, 1024);
  transpose_to_bf16<<<dim3(128, 32), tb, 0, stream>>>(w_f1, Bt_f1, 1024, 4096, 4096);
  transpose_to_bf16<<<dim3(32, 128), tb, 0, stream>>>(w_f2, Bt_f2, 4096, 1024, 1024);
  pack3<<<4, 256, 0, stream>>>(bq, bk, bv, bqkv, 1024);
  cvt_f32_bf16<<<2048, 256, 0, stream>>>(x, xb, 42467328L);

  // --- smolgen ---
  gemm_kernel<EP_SILU, false><<<dim3(324, 1), 256, 0, stream>>>(
      xb, Bt_c, 41472, 32, 1024, b_c, nullptr, nullptr, nullptr, h0b);
  zero_f32<<<512, 256, 0, stream>>>(pre_s, 131072);
  gemm_splitk<<<dim3(4, 2, 9), 256, 0, stream>>>(
      h0b, Bt_d1, 512, 256, 2592, 288, b_d1, pre_s);
  ln_rows<1><<<512, 256, 0, stream>>>(pre_s, ln1sg, ln1sb, h1b, 256);
  gemm_kernel<EP_NONE, true><<<dim3(4, 32), 256, 0, stream>>>(
      h1b, Bt_d2, 512, 4096, 256, b_d2, nullptr, nullptr, pre_s, nullptr);
  ln_rows<1><<<512, 256, 0, stream>>>(pre_s, ln2sg, ln2sb, h2b, 4096);
  gemm256<EP_NONE><<<32 * 26, 512, 0, stream>>>(
      h2b, Bt_gg, 6656, 6561, 256, 26, b_gg, nullptr, nullptr, smol);

  // --- attention ---
  gemm256<EP_NONE><<<162 * 12, 512, 0, stream>>>(
      xb, Bt_qkv, 3072, 3072, 1024, 12, bqkv, nullptr, nullptr, qkvb);
  attn_mfma<<<dim3(512, 16), 384, 0, stream>>>(qkvb, smol, aob);
  gemm256<EP_RESB><<<162 * 4, 512, 0, stream>>>(
      aob, Bt_wo, 1024, 1024, 1024, 4, bo, nullptr, xb, preln1);
  ln1024<false, true><<<41472, 256, 0, stream>>>(preln1, ln1g, ln1b, nullptr, hmidb);

  // --- FFN ---
  gemm256<EP_MISH><<<162 * 16, 512, 0, stream>>>(
      hmidb, Bt_f1, 4096, 4096, 1024, 16, b_f1, nullptr, nullptr, fb);
  gemm256<EP_RESB><<<162 * 4, 512, 0, stream>>>(
      fb, Bt_f2, 1024, 1024, 4096, 4, b_f2, nullptr, hmidb, preln2);
  ln1024<true, false><<<41472, 256, 0, stream>>>(preln2, flng, flnb, out, nullptr);
}